// Round 5
// baseline (663.015 us; speedup 1.0000x reference)
//
#include <hip/hip_runtime.h>
#include <stdint.h>

#define NB 4
#define SEQ 2048
#define DM 1024
#define NH 16
#define NDQK 20
#define NDV 64
#define DLQ 256
#define DLKV 128
#define MR (NB*SEQ)       // 8192 rows
#define NKV (NH*DLKV)     // 2048

typedef __attribute__((ext_vector_type(8))) short bf8;   // 8 bf16 (4 VGPR) MFMA A/B frag
typedef __attribute__((ext_vector_type(4))) float f4;    // MFMA C/D frag
typedef __attribute__((ext_vector_type(4))) short s4;

#define MFMA16(a,b,c) __builtin_amdgcn_mfma_f32_16x16x32_bf16(a, b, c, 0, 0, 0)

__device__ __forceinline__ short f2b(float f) {  // f32 -> bf16 RNE
  union { float f; unsigned u; } v; v.f = f;
  return (short)((v.u + 0x7FFFu + ((v.u >> 16) & 1u)) >> 16);
}

__device__ __forceinline__ void gld16(void* lds, const void* g) {
  __builtin_amdgcn_global_load_lds((const __attribute__((address_space(1))) void*)g,
                                   (__attribute__((address_space(3))) void*)lds, 16, 0, 0);
}

// 16-lane max reduce on the VALU pipe (DPP), not LDS.
__device__ __forceinline__ float dppmax16(float v) {
  int t;
  t = __builtin_amdgcn_update_dpp(0, __float_as_int(v), 0xB1,  0xF, 0xF, true); v = fmaxf(v, __int_as_float(t));
  t = __builtin_amdgcn_update_dpp(0, __float_as_int(v), 0x4E,  0xF, 0xF, true); v = fmaxf(v, __int_as_float(t));
  t = __builtin_amdgcn_update_dpp(0, __float_as_int(v), 0x141, 0xF, 0xF, true); v = fmaxf(v, __int_as_float(t));
  t = __builtin_amdgcn_update_dpp(0, __float_as_int(v), 0x140, 0xF, 0xF, true); v = fmaxf(v, __int_as_float(t));
  return v;
}

// ---------------- convert h / wq_a / wkv_a to bf16 ----------------
__global__ __launch_bounds__(256) void k_conv(const float* __restrict__ h,
    const float* __restrict__ wqa, const float* __restrict__ wkva,
    short* __restrict__ hb, short* __restrict__ wqab, short* __restrict__ wkvab) {
  const int NH4 = (MR*DM)/4, NQ4 = (DLQ*DM)/4, NK4 = (DLKV*DM)/4;
  int stride = gridDim.x * blockDim.x;
  for (int i = blockIdx.x*blockDim.x + threadIdx.x; i < NH4+NQ4+NK4; i += stride) {
    const float4* s; short* d; int o;
    if (i < NH4)            { s = (const float4*)h;    d = hb;     o = i; }
    else if (i < NH4+NQ4)   { s = (const float4*)wqa;  d = wqab;   o = i - NH4; }
    else                    { s = (const float4*)wkva; d = wkvab;  o = i - NH4 - NQ4; }
    float4 v = s[o];
    s4 r; r.x = f2b(v.x); r.y = f2b(v.y); r.z = f2b(v.z); r.w = f2b(v.w);
    *(s4*)(d + (size_t)o*4) = r;
  }
}

// ---------------- Wcomb[h*128+c][l] = scale*log2e * sum_q wq_b[h*20+q][l]*wkv_b[h][q][c] ----------------
__global__ __launch_bounds__(256) void k_wcomb(const float* __restrict__ wqbw,
    const float* __restrict__ wqbb, const float* __restrict__ wkvb,
    short* __restrict__ Wc, float* __restrict__ bc) {
  const float SC = 0.22360679774997896f * 1.4426950408889634f; // DQK^-0.5 * log2(e)
  int n = blockIdx.x, l = threadIdx.x;
  int hh = n >> 7, c = n & 127;
  float acc = 0.f, bacc = 0.f;
  for (int q = 0; q < NDQK; ++q) {
    float wv = wkvb[(hh*84 + q)*128 + c];
    acc  += wqbw[(hh*20 + q)*256 + l] * wv;
    bacc += wqbb[hh*20 + q] * wv;
  }
  Wc[(size_t)n*256 + l] = f2b(acc * SC);
  if (l == 0) bc[n] = bacc * SC;
}

// ---------------- W2[d][h*128+c] = sum_v wo[d][h*64+v]*wkv_b[h][20+v][c] ----------------
__global__ __launch_bounds__(256) void k_w2(const float* __restrict__ wo,
    const float* __restrict__ wkvb, short* __restrict__ W2) {
  int idx = blockIdx.x*256 + threadIdx.x;
  int d = idx >> 11, k = idx & 2047, hh = k >> 7, c = k & 127;
  float acc = 0.f;
  #pragma unroll 8
  for (int v = 0; v < NDV; ++v)
    acc += wo[d*1024 + hh*64 + v] * wkvb[(hh*84 + 20 + v)*128 + c];
  W2[idx] = f2b(acc);
}

// ---------------- fused latent projection + RMSnorm ----------------
template<int BN, bool WT>
__global__ __launch_bounds__(256) void k_proj_rms(const short* __restrict__ Ab,
    const short* __restrict__ Wb, const float* __restrict__ bias,
    const float* __restrict__ nw, short* __restrict__ outp, short* __restrict__ outT) {
  constexpr int WN = BN/4, NI = WN/16;
  __shared__ __align__(16) char As[32*128];
  __shared__ __align__(16) char Ws[BN*128];
  __shared__ float red[32][4];
  const int tid = threadIdx.x, l = tid & 63, w = tid >> 6;
  const int l15 = l & 15, l4 = l >> 4, l7 = l & 7, l3 = l >> 3;
  const int m0 = blockIdx.x * 32;
  f4 z = {0.f,0.f,0.f,0.f};
  f4 acc[2][NI];
  for (int mi=0;mi<2;mi++) for (int ni=0;ni<NI;ni++) acc[mi][ni] = z;
  for (int kt = 0; kt < DM/64; ++kt) {
    __syncthreads();
    { int row = w*8 + l3;
      gld16(As + w*1024 + l*16,
            (const char*)Ab + ((size_t)(m0+row)*DM + kt*64)*2 + ((l7 ^ (row&7))*16)); }
    #pragma unroll
    for (int i = 0; i < BN/32; ++i) {
      int ci = w*(BN/32) + i, row = ci*8 + l3;
      gld16(Ws + ci*1024 + l*16,
            (const char*)Wb + ((size_t)row*DM + kt*64)*2 + ((l7 ^ (row&7))*16));
    }
    asm volatile("s_waitcnt vmcnt(0)" ::: "memory");
    __syncthreads();
    #pragma unroll
    for (int kk = 0; kk < 2; ++kk) {
      bf8 a[2], bb[NI];
      #pragma unroll
      for (int mi=0;mi<2;mi++) { int row = mi*16 + l15;
        a[mi] = *(const bf8*)(As + row*128 + ((kk*64 + l4*16) ^ ((row&7)<<4))); }
      #pragma unroll
      for (int ni=0;ni<NI;ni++) { int n = w*WN + ni*16 + l15;
        bb[ni] = *(const bf8*)(Ws + n*128 + ((kk*64 + l4*16) ^ ((n&7)<<4))); }
      #pragma unroll
      for (int mi=0;mi<2;mi++)
        #pragma unroll
        for (int ni=0;ni<NI;ni++) acc[mi][ni] = MFMA16(a[mi], bb[ni], acc[mi][ni]);
    }
  }
  float bn[NI], nwv[NI];
  #pragma unroll
  for (int ni=0;ni<NI;ni++) { int n = w*WN + ni*16 + l15; bn[ni] = bias[n]; nwv[ni] = nw[n]; }
  #pragma unroll
  for (int mi=0;mi<2;mi++) {
    f4 v = z;
    #pragma unroll
    for (int ni=0;ni<NI;ni++)
      #pragma unroll
      for (int r=0;r<4;r++) { acc[mi][ni][r] += bn[ni]; v[r] += acc[mi][ni][r]*acc[mi][ni][r]; }
    #pragma unroll
    for (int r=0;r<4;r++)
      for (int x=1;x<16;x<<=1) v[r] += __shfl_xor(v[r], x);
    if (l15 == 0) {
      #pragma unroll
      for (int r=0;r<4;r++) red[mi*16 + l4*4 + r][w] = v[r];
    }
  }
  __syncthreads();
  #pragma unroll
  for (int mi=0;mi<2;mi++) {
    float sc[4];
    #pragma unroll
    for (int r=0;r<4;r++) { int row = mi*16 + l4*4 + r;
      float t = red[row][0] + red[row][1] + red[row][2] + red[row][3];
      sc[r] = rsqrtf(t * (1.0f/BN) + 1e-6f); }
    #pragma unroll
    for (int ni=0;ni<NI;ni++) { int n = w*WN + ni*16 + l15;
      #pragma unroll
      for (int r=0;r<4;r++) {
        int m = m0 + mi*16 + l4*4 + r;
        short bv = f2b(acc[mi][ni][r] * sc[r] * nwv[ni]);
        outp[(size_t)m*BN + n] = bv;
        if (WT) { int bb2 = m >> 11, s = m & 2047;
                  outT[((size_t)bb2*DLKV + n)*SEQ + s] = bv; }
      }
    }
  }
}

// ---------------- GEMM C[m][n] = A[m]·W[n] (+bias): BM=BN=128, BK=64, 4 waves ----------------
template<bool BOUT>
__global__ __launch_bounds__(256) void k_gemm(const short* __restrict__ A,
    const short* __restrict__ W, const float* __restrict__ bias,
    void* __restrict__ outp, int N, int K) {
  __shared__ __align__(16) char As[128*128];
  __shared__ __align__(16) char Ws[128*128];
  const int tid = threadIdx.x, l = tid & 63, w = tid >> 6;
  const int l15 = l&15, l4 = l>>4, l7 = l&7, l3 = l>>3;
  const int wm = w >> 1, wn = w & 1;
  const int n0 = blockIdx.x * 128, m0 = blockIdx.y * 128;
  f4 z = {0.f,0.f,0.f,0.f};
  f4 acc[4][4];
  for (int mi=0;mi<4;mi++) for (int ni=0;ni<4;ni++) acc[mi][ni] = z;
  for (int kt = 0; kt < (K>>6); ++kt) {
    __syncthreads();
    #pragma unroll
    for (int i=0;i<4;i++) {
      int ci = w*4 + i, row = ci*8 + l3;
      gld16(As + ci*1024 + l*16,
            (const char*)A + ((size_t)(m0+row)*K + kt*64)*2 + ((l7^(row&7))*16));
      gld16(Ws + ci*1024 + l*16,
            (const char*)W + ((size_t)(n0+row)*K + kt*64)*2 + ((l7^(row&7))*16));
    }
    asm volatile("s_waitcnt vmcnt(0)" ::: "memory");
    __syncthreads();
    #pragma unroll
    for (int kk=0;kk<2;kk++) {
      bf8 a[4], bb[4];
      #pragma unroll
      for (int mi=0;mi<4;mi++) { int row = wm*64+mi*16+l15;
        a[mi] = *(const bf8*)(As + row*128 + ((kk*64+l4*16)^((row&7)<<4))); }
      #pragma unroll
      for (int ni=0;ni<4;ni++) { int row = wn*64+ni*16+l15;
        bb[ni] = *(const bf8*)(Ws + row*128 + ((kk*64+l4*16)^((row&7)<<4))); }
      #pragma unroll
      for (int mi=0;mi<4;mi++)
        #pragma unroll
        for (int ni=0;ni<4;ni++) acc[mi][ni] = MFMA16(a[mi], bb[ni], acc[mi][ni]);
    }
  }
  #pragma unroll
  for (int ni=0;ni<4;ni++) {
    int n = n0 + wn*64 + ni*16 + l15;
    float bn = bias[n];
    #pragma unroll
    for (int mi=0;mi<4;mi++)
      #pragma unroll
      for (int r=0;r<4;r++) {
        int m = m0 + wm*64 + mi*16 + l4*4 + r;
        float val = acc[mi][ni][r] + bn;
        if (BOUT) ((short*)outp)[(size_t)m*N + n] = f2b(val);
        else      ((float*)outp)[(size_t)m*N + n] = val;
      }
  }
}

// ---------------- flash attention: 8 waves = 4 heads x 2 row-halves; 16 q-rows/wave ----------------
// 512 blocks x 512 thr, XCD-pinned batch, triangle-paired (y then 63-y), 2 blocks/CU -> 4 waves/SIMD.
// K: LDS dbuf via global_load_lds + counted vmcnt(2). V: global-direct. Defer-max rescale (THR=8).
__global__ __launch_bounds__(512, 4) void k_flash(const short* __restrict__ qkv,
    const short* __restrict__ kvn, const short* __restrict__ kvnT,
    short* __restrict__ vlat) {
  __shared__ __align__(16) char Ks[2][64*256];   // K tile [t][c] bf16, xor-swizzled, dbuf (32 KB)
  __shared__ __align__(16) short Pl[8][16*72];   // per-wave P: 16 rows x stride 72 (18 KB)
  const int tid = threadIdx.x, l = tid & 63, w = tid >> 6;
  const int l15 = l & 15, l4 = l >> 4;
  const int id = blockIdx.x;
  const int b   = (id & 7) >> 1;                  // XCD (id%8) pinned to one batch
  const int u   = ((id >> 3) << 1) | (id & 1);    // 0..127 within batch
  const int hg  = u & 3, y = u >> 2;              // 4 head-groups, 32 pairs
  const int hh  = hg*4 + (w & 3);                 // head
  const int half = w >> 2;                        // row-half within q-block
  const int qbs0 = y, qbs1 = 63 - y;
  const int ntA = (y >> 1) + 1, ntT = 33;
  const short* Kb = kvn  + (size_t)b*SEQ*DLKV;    // [t][c]
  const short* Vb = kvnT + (size_t)b*DLKV*SEQ;    // [c][t]
  short* Pw = Pl[w];

  const short ONE = 0x3F80;
  bf8 ones;
  #pragma unroll
  for (int j2=0;j2<8;j2++) ones[j2] = ONE;
  f4 z = {0.f,0.f,0.f,0.f};

  // ---- segment state (q-block A = light first) ----
  int qw = qbs0*32 + half*16;
  size_t rowbase = (size_t)b*SEQ + qw;
  bf8 qf[4];
  f4 acc[8], sums; float mr[4];
  #pragma unroll
  for (int kk=0;kk<4;kk++)
    qf[kk] = *(const bf8*)(qkv + (rowbase + l15)*NKV + hh*128 + kk*32 + l4*8);
  sums = z;
  #pragma unroll
  for (int cf=0;cf<8;cf++) acc[cf] = z;
  #pragma unroll
  for (int r=0;r<4;r++) mr[r] = -3.0e38f;

  // prologue: stage tile 0 into buf 0 (1024 16B chunks, 2 per thread)
  #pragma unroll
  for (int r=0;r<2;r++) {
    int ci = r*512 + tid, row = ci >> 4, c16 = ci & 15;
    gld16(Ks[0] + ci*16, (const char*)Kb + row*256 + ((c16 ^ (row & 7))*16));
  }
  int cur = 0, t = 0;
  for (int j = 0; j < ntT; ++j) {
    const int tn = (j+1 >= ntT) ? t : ((j+1 == ntA) ? 0 : t+1);
    {
      const char* src = (const char*)(Kb + (size_t)tn*64*DLKV);
      #pragma unroll
      for (int r=0;r<2;r++) {
        int ci = r*512 + tid, row = ci >> 4, c16 = ci & 15;
        gld16(Ks[cur^1] + ci*16, src + row*256 + ((c16 ^ (row & 7))*16));
      }
    }
    asm volatile("s_waitcnt vmcnt(2)" ::: "memory");
    __syncthreads();
    const int t0 = t*64;
    const char* kb = Ks[cur];
    // ---- scores = Q·K^T (exp2 domain, pre-scaled) ----
    f4 sc[4];
    #pragma unroll
    for (int tf=0;tf<4;tf++) sc[tf] = z;
    #pragma unroll
    for (int kk=0;kk<4;kk++) {
      bf8 bk[4];
      #pragma unroll
      for (int tf=0;tf<4;tf++) { int tt = tf*16 + l15;
        bk[tf] = *(const bf8*)(kb + tt*256 + ((kk*64 + l4*16) ^ ((tt&7)<<4))); }
      #pragma unroll
      for (int tf=0;tf<4;tf++) sc[tf] = MFMA16(qf[kk], bk[tf], sc[tf]);
    }
    // V prefetch (first half) — hides under softmax
    bf8 vr0[8], vr1[8];
    #pragma unroll
    for (int cf=0;cf<8;cf++)
      vr0[cf] = *(const bf8*)(Vb + (size_t)(cf*16 + l15)*SEQ + t0 + l4*8);
    if (t0 + 63 > qw) {   // diagonal: causal mask
      #pragma unroll
      for (int tf=0;tf<4;tf++)
        #pragma unroll
        for (int r=0;r<4;r++) {
          int qg = qw + l4*4 + r, tg = t0 + tf*16 + l15;
          if (tg > qg) sc[tf][r] = -3.0e38f;
        }
    }
    // ---- online softmax: DPP max + defer-max rescale ----
    float pmax[4];
    #pragma unroll
    for (int r=0;r<4;r++) {
      float v = fmaxf(fmaxf(sc[0][r], sc[1][r]), fmaxf(sc[2][r], sc[3][r]));
      pmax[r] = dppmax16(v);
    }
    bool need = false;
    #pragma unroll
    for (int r=0;r<4;r++) need = need || (pmax[r] > mr[r] + 8.0f);
    if (__any(need)) {
      #pragma unroll
      for (int r=0;r<4;r++) {
        float m2 = fmaxf(mr[r], pmax[r]);
        float al = exp2f(mr[r] - m2);
        mr[r] = m2;
        sums[r] *= al;
        #pragma unroll
        for (int cf=0;cf<8;cf++) acc[cf][r] *= al;
      }
    }
    #pragma unroll
    for (int tf=0;tf<4;tf++)
      #pragma unroll
      for (int r=0;r<4;r++)
        Pw[(l4*4 + r)*72 + tf*16 + l15] = f2b(exp2f(sc[tf][r] - mr[r]));
    // V prefetch (second half)
    #pragma unroll
    for (int cf=0;cf<8;cf++)
      vr1[cf] = *(const bf8*)(Vb + (size_t)(cf*16 + l15)*SEQ + t0 + 32 + l4*8);
    // ---- PV: acc += P·V, sums += P·1 ----
    #pragma unroll
    for (int kk=0;kk<2;kk++) {
      bf8 pa = *(const bf8*)(Pw + l15*72 + kk*32 + l4*8);
      sums = MFMA16(pa, ones, sums);
      #pragma unroll
      for (int cf=0;cf<8;cf++)
        acc[cf] = MFMA16(pa, kk ? vr1[cf] : vr0[cf], acc[cf]);
    }
    __syncthreads();   // protect Ks[cur] from next iteration's staging
    cur ^= 1;
    // ---- segment boundary: write out, reinit for q-block B ----
    if (j+1 == ntA || j+1 == ntT) {
      float inv[4];
      #pragma unroll
      for (int r=0;r<4;r++) inv[r] = 1.0f / sums[r];
      #pragma unroll
      for (int cf=0;cf<8;cf++)
        #pragma unroll
        for (int r=0;r<4;r++) {
          size_t m = rowbase + l4*4 + r;
          vlat[m*NKV + hh*128 + cf*16 + l15] = f2b(acc[cf][r] * inv[r]);
        }
      if (j+1 == ntA) {
        qw = qbs1*32 + half*16; rowbase = (size_t)b*SEQ + qw;
        #pragma unroll
        for (int kk=0;kk<4;kk++)
          qf[kk] = *(const bf8*)(qkv + (rowbase + l15)*NKV + hh*128 + kk*32 + l4*8);
        sums = z;
        #pragma unroll
        for (int cf=0;cf<8;cf++) acc[cf] = z;
        #pragma unroll
        for (int r=0;r<4;r++) mr[r] = -3.0e38f;
      }
    }
    t = tn;
  }
}

extern "C" void kernel_launch(void* const* d_in, const int* in_sizes, int n_in,
                              void* d_out, int out_size, void* d_ws, size_t ws_size,
                              hipStream_t stream) {
  const float* h     = (const float*)d_in[0];
  const float* wqaw  = (const float*)d_in[2];
  const float* wqa_b = (const float*)d_in[3];
  const float* qnw   = (const float*)d_in[4];
  const float* wqbw  = (const float*)d_in[5];
  const float* wqbb  = (const float*)d_in[6];
  const float* wkvaw = (const float*)d_in[7];
  const float* wkva_b= (const float*)d_in[8];
  const float* kvnw  = (const float*)d_in[9];
  const float* wkvb  = (const float*)d_in[10];
  const float* wow   = (const float*)d_in[11];
  const float* wob   = (const float*)d_in[12];

  char* ws = (char*)d_ws;
  size_t off = 0;
  auto alloc = [&](size_t bytes) { char* p = ws + off; off += (bytes + 255) & ~(size_t)255; return p; };
  short* hb     = (short*)alloc((size_t)MR*DM*2);
  short* wqab16 = (short*)alloc((size_t)DLQ*DM*2);
  short* wkvab16= (short*)alloc((size_t)DLKV*DM*2);
  short* qlat   = (short*)alloc((size_t)MR*DLQ*2);
  short* kvnb   = (short*)alloc((size_t)MR*DLKV*2);
  short* kvnT   = (short*)alloc((size_t)MR*DLKV*2);
  short* Wc     = (short*)alloc((size_t)NKV*DLQ*2);
  float* bc     = (float*)alloc((size_t)NKV*4);
  short* qkv    = (short*)alloc((size_t)MR*NKV*2);
  short* vlat   = (short*)alloc((size_t)MR*NKV*2);
  short* W2     = (short*)alloc((size_t)DM*NKV*2);

  k_conv<<<2048, 256, 0, stream>>>(h, wqaw, wkvaw, hb, wqab16, wkvab16);
  k_wcomb<<<NKV, 256, 0, stream>>>(wqbw, wqbb, wkvb, Wc, bc);
  k_w2<<<(DM*NKV)/256, 256, 0, stream>>>(wow, wkvb, W2);
  k_proj_rms<DLQ,  false><<<MR/32, 256, 0, stream>>>(hb, wqab16,  wqa_b,  qnw,  qlat, nullptr);
  k_proj_rms<DLKV, true ><<<MR/32, 256, 0, stream>>>(hb, wkvab16, wkva_b, kvnw, kvnb, kvnT);
  k_gemm<true ><<<dim3(NKV/128, MR/128), 256, 0, stream>>>(qlat, Wc, bc, qkv, NKV, DLQ);
  k_flash<<<512, 512, 0, stream>>>(qkv, kvnb, kvnT, vlat);
  k_gemm<false><<<dim3(DM/128, MR/128), 256, 0, stream>>>(vlat, W2, wob, d_out, DM, NKV);
}

// Round 6
// 582.935 us; speedup vs baseline: 1.1374x; 1.1374x over previous
//
#include <hip/hip_runtime.h>
#include <stdint.h>

#define NB 4
#define SEQ 2048
#define DM 1024
#define NH 16
#define NDQK 20
#define NDV 64
#define DLQ 256
#define DLKV 128
#define MR (NB*SEQ)       // 8192 rows
#define NKV (NH*DLKV)     // 2048

typedef __attribute__((ext_vector_type(8))) short bf8;   // 8 bf16 (4 VGPR) MFMA A/B frag
typedef __attribute__((ext_vector_type(4))) float f4;    // MFMA C/D frag
typedef __attribute__((ext_vector_type(4))) short s4;

#define MFMA16(a,b,c) __builtin_amdgcn_mfma_f32_16x16x32_bf16(a, b, c, 0, 0, 0)

__device__ __forceinline__ short f2b(float f) {  // f32 -> bf16 RNE
  union { float f; unsigned u; } v; v.f = f;
  return (short)((v.u + 0x7FFFu + ((v.u >> 16) & 1u)) >> 16);
}

__device__ __forceinline__ void gld16(void* lds, const void* g) {
  __builtin_amdgcn_global_load_lds((const __attribute__((address_space(1))) void*)g,
                                   (__attribute__((address_space(3))) void*)lds, 16, 0, 0);
}

// 16-lane max reduce on the VALU pipe (DPP), not LDS.
__device__ __forceinline__ float dppmax16(float v) {
  int t;
  t = __builtin_amdgcn_update_dpp(0, __float_as_int(v), 0xB1,  0xF, 0xF, true); v = fmaxf(v, __int_as_float(t));
  t = __builtin_amdgcn_update_dpp(0, __float_as_int(v), 0x4E,  0xF, 0xF, true); v = fmaxf(v, __int_as_float(t));
  t = __builtin_amdgcn_update_dpp(0, __float_as_int(v), 0x141, 0xF, 0xF, true); v = fmaxf(v, __int_as_float(t));
  t = __builtin_amdgcn_update_dpp(0, __float_as_int(v), 0x140, 0xF, 0xF, true); v = fmaxf(v, __int_as_float(t));
  return v;
}

// ---------------- convert h / wq_a / wkv_a to bf16 ----------------
__global__ __launch_bounds__(256) void k_conv(const float* __restrict__ h,
    const float* __restrict__ wqa, const float* __restrict__ wkva,
    short* __restrict__ hb, short* __restrict__ wqab, short* __restrict__ wkvab) {
  const int NH4 = (MR*DM)/4, NQ4 = (DLQ*DM)/4, NK4 = (DLKV*DM)/4;
  int stride = gridDim.x * blockDim.x;
  for (int i = blockIdx.x*blockDim.x + threadIdx.x; i < NH4+NQ4+NK4; i += stride) {
    const float4* s; short* d; int o;
    if (i < NH4)            { s = (const float4*)h;    d = hb;     o = i; }
    else if (i < NH4+NQ4)   { s = (const float4*)wqa;  d = wqab;   o = i - NH4; }
    else                    { s = (const float4*)wkva; d = wkvab;  o = i - NH4 - NQ4; }
    float4 v = s[o];
    s4 r; r.x = f2b(v.x); r.y = f2b(v.y); r.z = f2b(v.z); r.w = f2b(v.w);
    *(s4*)(d + (size_t)o*4) = r;
  }
}

// ---------------- Wcomb[h*128+c][l] = scale*log2e * sum_q wq_b[h*20+q][l]*wkv_b[h][q][c] ----------------
__global__ __launch_bounds__(256) void k_wcomb(const float* __restrict__ wqbw,
    const float* __restrict__ wqbb, const float* __restrict__ wkvb,
    short* __restrict__ Wc, float* __restrict__ bc) {
  const float SC = 0.22360679774997896f * 1.4426950408889634f; // DQK^-0.5 * log2(e)
  int n = blockIdx.x, l = threadIdx.x;
  int hh = n >> 7, c = n & 127;
  float acc = 0.f, bacc = 0.f;
  for (int q = 0; q < NDQK; ++q) {
    float wv = wkvb[(hh*84 + q)*128 + c];
    acc  += wqbw[(hh*20 + q)*256 + l] * wv;
    bacc += wqbb[hh*20 + q] * wv;
  }
  Wc[(size_t)n*256 + l] = f2b(acc * SC);
  if (l == 0) bc[n] = bacc * SC;
}

// ---------------- W2[d][h*128+c] = sum_v wo[d][h*64+v]*wkv_b[h][20+v][c] ----------------
__global__ __launch_bounds__(256) void k_w2(const float* __restrict__ wo,
    const float* __restrict__ wkvb, short* __restrict__ W2) {
  int idx = blockIdx.x*256 + threadIdx.x;
  int d = idx >> 11, k = idx & 2047, hh = k >> 7, c = k & 127;
  float acc = 0.f;
  #pragma unroll 8
  for (int v = 0; v < NDV; ++v)
    acc += wo[d*1024 + hh*64 + v] * wkvb[(hh*84 + 20 + v)*128 + c];
  W2[idx] = f2b(acc);
}

// ---------------- fused latent projection + RMSnorm ----------------
template<int BN, bool WT>
__global__ __launch_bounds__(256) void k_proj_rms(const short* __restrict__ Ab,
    const short* __restrict__ Wb, const float* __restrict__ bias,
    const float* __restrict__ nw, short* __restrict__ outp, short* __restrict__ outT) {
  constexpr int WN = BN/4, NI = WN/16;
  __shared__ __align__(16) char As[32*128];
  __shared__ __align__(16) char Ws[BN*128];
  __shared__ float red[32][4];
  const int tid = threadIdx.x, l = tid & 63, w = tid >> 6;
  const int l15 = l & 15, l4 = l >> 4, l7 = l & 7, l3 = l >> 3;
  const int m0 = blockIdx.x * 32;
  f4 z = {0.f,0.f,0.f,0.f};
  f4 acc[2][NI];
  for (int mi=0;mi<2;mi++) for (int ni=0;ni<NI;ni++) acc[mi][ni] = z;
  for (int kt = 0; kt < DM/64; ++kt) {
    __syncthreads();
    { int row = w*8 + l3;
      gld16(As + w*1024 + l*16,
            (const char*)Ab + ((size_t)(m0+row)*DM + kt*64)*2 + ((l7 ^ (row&7))*16)); }
    #pragma unroll
    for (int i = 0; i < BN/32; ++i) {
      int ci = w*(BN/32) + i, row = ci*8 + l3;
      gld16(Ws + ci*1024 + l*16,
            (const char*)Wb + ((size_t)row*DM + kt*64)*2 + ((l7 ^ (row&7))*16));
    }
    asm volatile("s_waitcnt vmcnt(0)" ::: "memory");
    __syncthreads();
    #pragma unroll
    for (int kk = 0; kk < 2; ++kk) {
      bf8 a[2], bb[NI];
      #pragma unroll
      for (int mi=0;mi<2;mi++) { int row = mi*16 + l15;
        a[mi] = *(const bf8*)(As + row*128 + ((kk*64 + l4*16) ^ ((row&7)<<4))); }
      #pragma unroll
      for (int ni=0;ni<NI;ni++) { int n = w*WN + ni*16 + l15;
        bb[ni] = *(const bf8*)(Ws + n*128 + ((kk*64 + l4*16) ^ ((n&7)<<4))); }
      #pragma unroll
      for (int mi=0;mi<2;mi++)
        #pragma unroll
        for (int ni=0;ni<NI;ni++) acc[mi][ni] = MFMA16(a[mi], bb[ni], acc[mi][ni]);
    }
  }
  float bn[NI], nwv[NI];
  #pragma unroll
  for (int ni=0;ni<NI;ni++) { int n = w*WN + ni*16 + l15; bn[ni] = bias[n]; nwv[ni] = nw[n]; }
  #pragma unroll
  for (int mi=0;mi<2;mi++) {
    f4 v = z;
    #pragma unroll
    for (int ni=0;ni<NI;ni++)
      #pragma unroll
      for (int r=0;r<4;r++) { acc[mi][ni][r] += bn[ni]; v[r] += acc[mi][ni][r]*acc[mi][ni][r]; }
    #pragma unroll
    for (int r=0;r<4;r++)
      for (int x=1;x<16;x<<=1) v[r] += __shfl_xor(v[r], x);
    if (l15 == 0) {
      #pragma unroll
      for (int r=0;r<4;r++) red[mi*16 + l4*4 + r][w] = v[r];
    }
  }
  __syncthreads();
  #pragma unroll
  for (int mi=0;mi<2;mi++) {
    float sc[4];
    #pragma unroll
    for (int r=0;r<4;r++) { int row = mi*16 + l4*4 + r;
      float t = red[row][0] + red[row][1] + red[row][2] + red[row][3];
      sc[r] = rsqrtf(t * (1.0f/BN) + 1e-6f); }
    #pragma unroll
    for (int ni=0;ni<NI;ni++) { int n = w*WN + ni*16 + l15;
      #pragma unroll
      for (int r=0;r<4;r++) {
        int m = m0 + mi*16 + l4*4 + r;
        short bv = f2b(acc[mi][ni][r] * sc[r] * nwv[ni]);
        outp[(size_t)m*BN + n] = bv;
        if (WT) { int bb2 = m >> 11, s = m & 2047;
                  outT[((size_t)bb2*DLKV + n)*SEQ + s] = bv; }
      }
    }
  }
}

// ---------------- GEMM C[m][n] = A[m]·W[n] (+bias): BM=BN=128, BK=64, 4 waves ----------------
template<bool BOUT>
__global__ __launch_bounds__(256) void k_gemm(const short* __restrict__ A,
    const short* __restrict__ W, const float* __restrict__ bias,
    void* __restrict__ outp, int N, int K) {
  __shared__ __align__(16) char As[128*128];
  __shared__ __align__(16) char Ws[128*128];
  const int tid = threadIdx.x, l = tid & 63, w = tid >> 6;
  const int l15 = l&15, l4 = l>>4, l7 = l&7, l3 = l>>3;
  const int wm = w >> 1, wn = w & 1;
  const int n0 = blockIdx.x * 128, m0 = blockIdx.y * 128;
  f4 z = {0.f,0.f,0.f,0.f};
  f4 acc[4][4];
  for (int mi=0;mi<4;mi++) for (int ni=0;ni<4;ni++) acc[mi][ni] = z;
  for (int kt = 0; kt < (K>>6); ++kt) {
    __syncthreads();
    #pragma unroll
    for (int i=0;i<4;i++) {
      int ci = w*4 + i, row = ci*8 + l3;
      gld16(As + ci*1024 + l*16,
            (const char*)A + ((size_t)(m0+row)*K + kt*64)*2 + ((l7^(row&7))*16));
      gld16(Ws + ci*1024 + l*16,
            (const char*)W + ((size_t)(n0+row)*K + kt*64)*2 + ((l7^(row&7))*16));
    }
    asm volatile("s_waitcnt vmcnt(0)" ::: "memory");
    __syncthreads();
    #pragma unroll
    for (int kk=0;kk<2;kk++) {
      bf8 a[4], bb[4];
      #pragma unroll
      for (int mi=0;mi<4;mi++) { int row = wm*64+mi*16+l15;
        a[mi] = *(const bf8*)(As + row*128 + ((kk*64+l4*16)^((row&7)<<4))); }
      #pragma unroll
      for (int ni=0;ni<4;ni++) { int row = wn*64+ni*16+l15;
        bb[ni] = *(const bf8*)(Ws + row*128 + ((kk*64+l4*16)^((row&7)<<4))); }
      #pragma unroll
      for (int mi=0;mi<4;mi++)
        #pragma unroll
        for (int ni=0;ni<4;ni++) acc[mi][ni] = MFMA16(a[mi], bb[ni], acc[mi][ni]);
    }
  }
  #pragma unroll
  for (int ni=0;ni<4;ni++) {
    int n = n0 + wn*64 + ni*16 + l15;
    float bn = bias[n];
    #pragma unroll
    for (int mi=0;mi<4;mi++)
      #pragma unroll
      for (int r=0;r<4;r++) {
        int m = m0 + wm*64 + mi*16 + l4*4 + r;
        float val = acc[mi][ni][r] + bn;
        if (BOUT) ((short*)outp)[(size_t)m*N + n] = f2b(val);
        else      ((float*)outp)[(size_t)m*N + n] = val;
      }
  }
}

// ---------------- flash attention: 8 waves = 4 heads x 2 row-halves; 16 q-rows/wave ----------------
// 512 blocks x 512 thr, XCD-pinned batch, triangle-paired (y then 63-y).
// launch_bounds(512,2): natural VGPR (~110) <= 128 -> 2 blocks/CU = 4 waves/SIMD, NO spills.
// K: LDS dbuf via global_load_lds + counted vmcnt(2). V: global-direct, loaded inline in PV.
__global__ __launch_bounds__(512, 2) void k_flash(const short* __restrict__ qkv,
    const short* __restrict__ kvn, const short* __restrict__ kvnT,
    short* __restrict__ vlat) {
  __shared__ __align__(16) char Ks[2][64*256];   // K tile [t][c] bf16, xor-swizzled, dbuf (32 KB)
  __shared__ __align__(16) short Pl[8][16*72];   // per-wave P: 16 rows x stride 72 (18 KB)
  const int tid = threadIdx.x, l = tid & 63, w = tid >> 6;
  const int l15 = l & 15, l4 = l >> 4;
  const int id = blockIdx.x;
  const int b   = (id & 7) >> 1;                  // XCD (id%8) pinned to one batch
  const int u   = ((id >> 3) << 1) | (id & 1);    // 0..127 within batch
  const int hg  = u & 3, y = u >> 2;              // 4 head-groups, 32 pairs
  const int hh  = hg*4 + (w & 3);                 // head
  const int half = w >> 2;                        // row-half within q-block
  const int qbs0 = y, qbs1 = 63 - y;
  const int ntA = (y >> 1) + 1, ntT = 33;
  const short* Kb = kvn  + (size_t)b*SEQ*DLKV;    // [t][c]
  const short* Vb = kvnT + (size_t)b*DLKV*SEQ;    // [c][t]
  short* Pw = Pl[w];

  const short ONE = 0x3F80;
  bf8 ones;
  #pragma unroll
  for (int j2=0;j2<8;j2++) ones[j2] = ONE;
  f4 z = {0.f,0.f,0.f,0.f};

  // ---- segment state (q-block A = light first) ----
  int qw = qbs0*32 + half*16;
  size_t rowbase = (size_t)b*SEQ + qw;
  bf8 qf[4];
  f4 acc[8], sums; float mr[4];
  #pragma unroll
  for (int kk=0;kk<4;kk++)
    qf[kk] = *(const bf8*)(qkv + (rowbase + l15)*NKV + hh*128 + kk*32 + l4*8);
  sums = z;
  #pragma unroll
  for (int cf=0;cf<8;cf++) acc[cf] = z;
  #pragma unroll
  for (int r=0;r<4;r++) mr[r] = -3.0e38f;

  // prologue: stage tile 0 into buf 0 (1024 16B chunks, 2 per thread)
  #pragma unroll
  for (int r=0;r<2;r++) {
    int ci = r*512 + tid, row = ci >> 4, c16 = ci & 15;
    gld16(Ks[0] + ci*16, (const char*)Kb + row*256 + ((c16 ^ (row & 7))*16));
  }
  int cur = 0, t = 0;
  for (int j = 0; j < ntT; ++j) {
    const int tn = (j+1 >= ntT) ? t : ((j+1 == ntA) ? 0 : t+1);
    {
      const char* src = (const char*)(Kb + (size_t)tn*64*DLKV);
      #pragma unroll
      for (int r=0;r<2;r++) {
        int ci = r*512 + tid, row = ci >> 4, c16 = ci & 15;
        gld16(Ks[cur^1] + ci*16, src + row*256 + ((c16 ^ (row & 7))*16));
      }
    }
    asm volatile("s_waitcnt vmcnt(2)" ::: "memory");
    __syncthreads();
    const int t0 = t*64;
    const char* kb = Ks[cur];
    // ---- scores = Q·K^T (exp2 domain, pre-scaled) ----
    f4 sc[4];
    #pragma unroll
    for (int tf=0;tf<4;tf++) sc[tf] = z;
    #pragma unroll
    for (int kk=0;kk<4;kk++) {
      bf8 bk[4];
      #pragma unroll
      for (int tf=0;tf<4;tf++) { int tt = tf*16 + l15;
        bk[tf] = *(const bf8*)(kb + tt*256 + ((kk*64 + l4*16) ^ ((tt&7)<<4))); }
      #pragma unroll
      for (int tf=0;tf<4;tf++) sc[tf] = MFMA16(qf[kk], bk[tf], sc[tf]);
    }
    if (t0 + 63 > qw) {   // diagonal: causal mask
      #pragma unroll
      for (int tf=0;tf<4;tf++)
        #pragma unroll
        for (int r=0;r<4;r++) {
          int qg = qw + l4*4 + r, tg = t0 + tf*16 + l15;
          if (tg > qg) sc[tf][r] = -3.0e38f;
        }
    }
    // ---- online softmax: DPP max + defer-max rescale ----
    float pmax[4];
    #pragma unroll
    for (int r=0;r<4;r++) {
      float v = fmaxf(fmaxf(sc[0][r], sc[1][r]), fmaxf(sc[2][r], sc[3][r]));
      pmax[r] = dppmax16(v);
    }
    bool need = false;
    #pragma unroll
    for (int r=0;r<4;r++) need = need || (pmax[r] > mr[r] + 8.0f);
    if (__any(need)) {
      #pragma unroll
      for (int r=0;r<4;r++) {
        float m2 = fmaxf(mr[r], pmax[r]);
        float al = exp2f(mr[r] - m2);
        mr[r] = m2;
        sums[r] *= al;
        #pragma unroll
        for (int cf=0;cf<8;cf++) acc[cf][r] *= al;
      }
    }
    #pragma unroll
    for (int tf=0;tf<4;tf++)
      #pragma unroll
      for (int r=0;r<4;r++)
        Pw[(l4*4 + r)*72 + tf*16 + l15] = f2b(exp2f(sc[tf][r] - mr[r]));
    // ---- PV: acc += P·V, sums += P·1 ; V loaded inline (L2-resident, XCD-pinned) ----
    #pragma unroll
    for (int kk=0;kk<2;kk++) {
      bf8 pa = *(const bf8*)(Pw + l15*72 + kk*32 + l4*8);
      sums = MFMA16(pa, ones, sums);
      #pragma unroll
      for (int cf=0;cf<8;cf++) {
        bf8 bv = *(const bf8*)(Vb + (size_t)(cf*16 + l15)*SEQ + t0 + kk*32 + l4*8);
        acc[cf] = MFMA16(pa, bv, acc[cf]);
      }
    }
    __syncthreads();   // protect Ks[cur] from next iteration's staging
    cur ^= 1;
    // ---- segment boundary: write out, reinit for q-block B ----
    if (j+1 == ntA || j+1 == ntT) {
      float inv[4];
      #pragma unroll
      for (int r=0;r<4;r++) inv[r] = 1.0f / sums[r];
      #pragma unroll
      for (int cf=0;cf<8;cf++)
        #pragma unroll
        for (int r=0;r<4;r++) {
          size_t m = rowbase + l4*4 + r;
          vlat[m*NKV + hh*128 + cf*16 + l15] = f2b(acc[cf][r] * inv[r]);
        }
      if (j+1 == ntA) {
        qw = qbs1*32 + half*16; rowbase = (size_t)b*SEQ + qw;
        #pragma unroll
        for (int kk=0;kk<4;kk++)
          qf[kk] = *(const bf8*)(qkv + (rowbase + l15)*NKV + hh*128 + kk*32 + l4*8);
        sums = z;
        #pragma unroll
        for (int cf=0;cf<8;cf++) acc[cf] = z;
        #pragma unroll
        for (int r=0;r<4;r++) mr[r] = -3.0e38f;
      }
    }
    t = tn;
  }
}

extern "C" void kernel_launch(void* const* d_in, const int* in_sizes, int n_in,
                              void* d_out, int out_size, void* d_ws, size_t ws_size,
                              hipStream_t stream) {
  const float* h     = (const float*)d_in[0];
  const float* wqaw  = (const float*)d_in[2];
  const float* wqa_b = (const float*)d_in[3];
  const float* qnw   = (const float*)d_in[4];
  const float* wqbw  = (const float*)d_in[5];
  const float* wqbb  = (const float*)d_in[6];
  const float* wkvaw = (const float*)d_in[7];
  const float* wkva_b= (const float*)d_in[8];
  const float* kvnw  = (const float*)d_in[9];
  const float* wkvb  = (const float*)d_in[10];
  const float* wow   = (const float*)d_in[11];
  const float* wob   = (const float*)d_in[12];

  char* ws = (char*)d_ws;
  size_t off = 0;
  auto alloc = [&](size_t bytes) { char* p = ws + off; off += (bytes + 255) & ~(size_t)255; return p; };
  short* hb     = (short*)alloc((size_t)MR*DM*2);
  short* wqab16 = (short*)alloc((size_t)DLQ*DM*2);
  short* wkvab16= (short*)alloc((size_t)DLKV*DM*2);
  short* qlat   = (short*)alloc((size_t)MR*DLQ*2);
  short* kvnb   = (short*)alloc((size_t)MR*DLKV*2);
  short* kvnT   = (short*)alloc((size_t)MR*DLKV*2);
  short* Wc     = (short*)alloc((size_t)NKV*DLQ*2);
  float* bc     = (float*)alloc((size_t)NKV*4);
  short* qkv    = (short*)alloc((size_t)MR*NKV*2);
  short* vlat   = (short*)alloc((size_t)MR*NKV*2);
  short* W2     = (short*)alloc((size_t)DM*NKV*2);

  k_conv<<<2048, 256, 0, stream>>>(h, wqaw, wkvaw, hb, wqab16, wkvab16);
  k_wcomb<<<NKV, 256, 0, stream>>>(wqbw, wqbb, wkvb, Wc, bc);
  k_w2<<<(DM*NKV)/256, 256, 0, stream>>>(wow, wkvb, W2);
  k_proj_rms<DLQ,  false><<<MR/32, 256, 0, stream>>>(hb, wqab16,  wqa_b,  qnw,  qlat, nullptr);
  k_proj_rms<DLKV, true ><<<MR/32, 256, 0, stream>>>(hb, wkvab16, wkva_b, kvnw, kvnb, kvnT);
  k_gemm<true ><<<dim3(NKV/128, MR/128), 256, 0, stream>>>(qlat, Wc, bc, qkv, NKV, DLQ);
  k_flash<<<512, 512, 0, stream>>>(qkv, kvnb, kvnT, vlat);
  k_gemm<false><<<dim3(DM/128, MR/128), 256, 0, stream>>>(vlat, W2, wob, d_out, DM, NKV);
}

// Round 7
// 570.805 us; speedup vs baseline: 1.1615x; 1.0213x over previous
//
#include <hip/hip_runtime.h>
#include <stdint.h>

#define NB 4
#define SEQ 2048
#define DM 1024
#define NH 16
#define NDQK 20
#define NDV 64
#define DLQ 256
#define DLKV 128
#define MR (NB*SEQ)       // 8192 rows
#define NKV (NH*DLKV)     // 2048

typedef __attribute__((ext_vector_type(8))) short bf8;   // 8 bf16 (4 VGPR) MFMA A/B frag
typedef __attribute__((ext_vector_type(4))) float f4;    // MFMA C/D frag
typedef __attribute__((ext_vector_type(4))) short s4;
typedef __attribute__((ext_vector_type(2))) unsigned int u2;

#define MFMA16(a,b,c) __builtin_amdgcn_mfma_f32_16x16x32_bf16(a, b, c, 0, 0, 0)

__device__ __forceinline__ short f2b(float f) {  // f32 -> bf16 RNE
  union { float f; unsigned u; } v; v.f = f;
  return (short)((v.u + 0x7FFFu + ((v.u >> 16) & 1u)) >> 16);
}

__device__ __forceinline__ unsigned cvtpk(float lo, float hi) { // 2xf32 -> packed bf16x2 (RNE)
  unsigned d; asm("v_cvt_pk_bf16_f32 %0, %1, %2" : "=v"(d) : "v"(lo), "v"(hi)); return d;
}

__device__ __forceinline__ void gld16(void* lds, const void* g) {
  __builtin_amdgcn_global_load_lds((const __attribute__((address_space(1))) void*)g,
                                   (__attribute__((address_space(3))) void*)lds, 16, 0, 0);
}

// ---------------- convert h / wq_a / wkv_a to bf16 ----------------
__global__ __launch_bounds__(256) void k_conv(const float* __restrict__ h,
    const float* __restrict__ wqa, const float* __restrict__ wkva,
    short* __restrict__ hb, short* __restrict__ wqab, short* __restrict__ wkvab) {
  const int NH4 = (MR*DM)/4, NQ4 = (DLQ*DM)/4, NK4 = (DLKV*DM)/4;
  int stride = gridDim.x * blockDim.x;
  for (int i = blockIdx.x*blockDim.x + threadIdx.x; i < NH4+NQ4+NK4; i += stride) {
    const float4* s; short* d; int o;
    if (i < NH4)            { s = (const float4*)h;    d = hb;     o = i; }
    else if (i < NH4+NQ4)   { s = (const float4*)wqa;  d = wqab;   o = i - NH4; }
    else                    { s = (const float4*)wkva; d = wkvab;  o = i - NH4 - NQ4; }
    float4 v = s[o];
    s4 r; r.x = f2b(v.x); r.y = f2b(v.y); r.z = f2b(v.z); r.w = f2b(v.w);
    *(s4*)(d + (size_t)o*4) = r;
  }
}

// ---------------- Wcomb[h*128+c][l] = scale*log2e * sum_q wq_b[h*20+q][l]*wkv_b[h][q][c] ----------------
__global__ __launch_bounds__(256) void k_wcomb(const float* __restrict__ wqbw,
    const float* __restrict__ wqbb, const float* __restrict__ wkvb,
    short* __restrict__ Wc, float* __restrict__ bc) {
  const float SC = 0.22360679774997896f * 1.4426950408889634f; // DQK^-0.5 * log2(e)
  int n = blockIdx.x, l = threadIdx.x;
  int hh = n >> 7, c = n & 127;
  float acc = 0.f, bacc = 0.f;
  for (int q = 0; q < NDQK; ++q) {
    float wv = wkvb[(hh*84 + q)*128 + c];
    acc  += wqbw[(hh*20 + q)*256 + l] * wv;
    bacc += wqbb[hh*20 + q] * wv;
  }
  Wc[(size_t)n*256 + l] = f2b(acc * SC);
  if (l == 0) bc[n] = bacc * SC;
}

// ---------------- W2[d][h*128+c] = sum_v wo[d][h*64+v]*wkv_b[h][20+v][c] ----------------
__global__ __launch_bounds__(256) void k_w2(const float* __restrict__ wo,
    const float* __restrict__ wkvb, short* __restrict__ W2) {
  int idx = blockIdx.x*256 + threadIdx.x;
  int d = idx >> 11, k = idx & 2047, hh = k >> 7, c = k & 127;
  float acc = 0.f;
  #pragma unroll 8
  for (int v = 0; v < NDV; ++v)
    acc += wo[d*1024 + hh*64 + v] * wkvb[(hh*84 + 20 + v)*128 + c];
  W2[idx] = f2b(acc);
}

// ---------------- fused latent projection + RMSnorm ----------------
template<int BN, bool WT>
__global__ __launch_bounds__(256) void k_proj_rms(const short* __restrict__ Ab,
    const short* __restrict__ Wb, const float* __restrict__ bias,
    const float* __restrict__ nw, short* __restrict__ outp, short* __restrict__ outT) {
  constexpr int WN = BN/4, NI = WN/16;
  __shared__ __align__(16) char As[32*128];
  __shared__ __align__(16) char Ws[BN*128];
  __shared__ float red[32][4];
  const int tid = threadIdx.x, l = tid & 63, w = tid >> 6;
  const int l15 = l & 15, l4 = l >> 4, l7 = l & 7, l3 = l >> 3;
  const int m0 = blockIdx.x * 32;
  f4 z = {0.f,0.f,0.f,0.f};
  f4 acc[2][NI];
  for (int mi=0;mi<2;mi++) for (int ni=0;ni<NI;ni++) acc[mi][ni] = z;
  for (int kt = 0; kt < DM/64; ++kt) {
    __syncthreads();
    { int row = w*8 + l3;
      gld16(As + w*1024 + l*16,
            (const char*)Ab + ((size_t)(m0+row)*DM + kt*64)*2 + ((l7 ^ (row&7))*16)); }
    #pragma unroll
    for (int i = 0; i < BN/32; ++i) {
      int ci = w*(BN/32) + i, row = ci*8 + l3;
      gld16(Ws + ci*1024 + l*16,
            (const char*)Wb + ((size_t)row*DM + kt*64)*2 + ((l7 ^ (row&7))*16));
    }
    asm volatile("s_waitcnt vmcnt(0)" ::: "memory");
    __syncthreads();
    #pragma unroll
    for (int kk = 0; kk < 2; ++kk) {
      bf8 a[2], bb[NI];
      #pragma unroll
      for (int mi=0;mi<2;mi++) { int row = mi*16 + l15;
        a[mi] = *(const bf8*)(As + row*128 + ((kk*64 + l4*16) ^ ((row&7)<<4))); }
      #pragma unroll
      for (int ni=0;ni<NI;ni++) { int n = w*WN + ni*16 + l15;
        bb[ni] = *(const bf8*)(Ws + n*128 + ((kk*64 + l4*16) ^ ((n&7)<<4))); }
      #pragma unroll
      for (int mi=0;mi<2;mi++)
        #pragma unroll
        for (int ni=0;ni<NI;ni++) acc[mi][ni] = MFMA16(a[mi], bb[ni], acc[mi][ni]);
    }
  }
  float bn[NI], nwv[NI];
  #pragma unroll
  for (int ni=0;ni<NI;ni++) { int n = w*WN + ni*16 + l15; bn[ni] = bias[n]; nwv[ni] = nw[n]; }
  #pragma unroll
  for (int mi=0;mi<2;mi++) {
    f4 v = z;
    #pragma unroll
    for (int ni=0;ni<NI;ni++)
      #pragma unroll
      for (int r=0;r<4;r++) { acc[mi][ni][r] += bn[ni]; v[r] += acc[mi][ni][r]*acc[mi][ni][r]; }
    #pragma unroll
    for (int r=0;r<4;r++)
      for (int x=1;x<16;x<<=1) v[r] += __shfl_xor(v[r], x);
    if (l15 == 0) {
      #pragma unroll
      for (int r=0;r<4;r++) red[mi*16 + l4*4 + r][w] = v[r];
    }
  }
  __syncthreads();
  #pragma unroll
  for (int mi=0;mi<2;mi++) {
    float sc[4];
    #pragma unroll
    for (int r=0;r<4;r++) { int row = mi*16 + l4*4 + r;
      float t = red[row][0] + red[row][1] + red[row][2] + red[row][3];
      sc[r] = rsqrtf(t * (1.0f/BN) + 1e-6f); }
    #pragma unroll
    for (int ni=0;ni<NI;ni++) { int n = w*WN + ni*16 + l15;
      #pragma unroll
      for (int r=0;r<4;r++) {
        int m = m0 + mi*16 + l4*4 + r;
        short bv = f2b(acc[mi][ni][r] * sc[r] * nwv[ni]);
        outp[(size_t)m*BN + n] = bv;
        if (WT) { int bb2 = m >> 11, s = m & 2047;
                  outT[((size_t)bb2*DLKV + n)*SEQ + s] = bv; }
      }
    }
  }
}

// ---------------- GEMM C[m][n] = A[m]·W[n] (+bias): BM=BN=128, BK=64, 4 waves ----------------
template<bool BOUT>
__global__ __launch_bounds__(256) void k_gemm(const short* __restrict__ A,
    const short* __restrict__ W, const float* __restrict__ bias,
    void* __restrict__ outp, int N, int K) {
  __shared__ __align__(16) char As[128*128];
  __shared__ __align__(16) char Ws[128*128];
  const int tid = threadIdx.x, l = tid & 63, w = tid >> 6;
  const int l15 = l&15, l4 = l>>4, l7 = l&7, l3 = l>>3;
  const int wm = w >> 1, wn = w & 1;
  const int n0 = blockIdx.x * 128, m0 = blockIdx.y * 128;
  f4 z = {0.f,0.f,0.f,0.f};
  f4 acc[4][4];
  for (int mi=0;mi<4;mi++) for (int ni=0;ni<4;ni++) acc[mi][ni] = z;
  for (int kt = 0; kt < (K>>6); ++kt) {
    __syncthreads();
    #pragma unroll
    for (int i=0;i<4;i++) {
      int ci = w*4 + i, row = ci*8 + l3;
      gld16(As + ci*1024 + l*16,
            (const char*)A + ((size_t)(m0+row)*K + kt*64)*2 + ((l7^(row&7))*16));
      gld16(Ws + ci*1024 + l*16,
            (const char*)W + ((size_t)(n0+row)*K + kt*64)*2 + ((l7^(row&7))*16));
    }
    asm volatile("s_waitcnt vmcnt(0)" ::: "memory");
    __syncthreads();
    #pragma unroll
    for (int kk=0;kk<2;kk++) {
      bf8 a[4], bb[4];
      #pragma unroll
      for (int mi=0;mi<4;mi++) { int row = wm*64+mi*16+l15;
        a[mi] = *(const bf8*)(As + row*128 + ((kk*64+l4*16)^((row&7)<<4))); }
      #pragma unroll
      for (int ni=0;ni<4;ni++) { int row = wn*64+ni*16+l15;
        bb[ni] = *(const bf8*)(Ws + row*128 + ((kk*64+l4*16)^((row&7)<<4))); }
      #pragma unroll
      for (int mi=0;mi<4;mi++)
        #pragma unroll
        for (int ni=0;ni<4;ni++) acc[mi][ni] = MFMA16(a[mi], bb[ni], acc[mi][ni]);
    }
  }
  #pragma unroll
  for (int ni=0;ni<4;ni++) {
    int n = n0 + wn*64 + ni*16 + l15;
    float bn = bias[n];
    #pragma unroll
    for (int mi=0;mi<4;mi++)
      #pragma unroll
      for (int r=0;r<4;r++) {
        int m = m0 + wm*64 + mi*16 + l4*4 + r;
        float val = acc[mi][ni][r] + bn;
        if (BOUT) ((short*)outp)[(size_t)m*N + n] = f2b(val);
        else      ((float*)outp)[(size_t)m*N + n] = val;
      }
  }
}

// ---------------- flash attention v7: 4 waves = 4 heads, 32 q-rows/wave, swapped QK^T ----------------
// 512 blocks x 256 thr, XCD-pinned batch, triangle-paired. LDS 50 KB -> 3 blocks/CU target.
// Swapped QK^T => P cols = q (lane&15), t in regs: cvt_pk pairs + ds_write_b64; defer-max.
__global__ __launch_bounds__(256, 3) void k_flash(const short* __restrict__ qkv,
    const short* __restrict__ kvn, const short* __restrict__ kvnT,
    short* __restrict__ vlat) {
  __shared__ __align__(16) char Ks[2][64*256];   // K tile [t][c] bf16, xor-swizzled, dbuf (32 KB)
  __shared__ __align__(16) short Pl[4][32*72];   // per-wave P: 32 rows x stride 72 shorts (18 KB)
  const int tid = threadIdx.x, l = tid & 63, w = tid >> 6;   // w = head-in-group
  const int l15 = l & 15, p = l >> 4;            // p = quadrant 0..3
  const int id = blockIdx.x;
  const int b   = (id & 7) >> 1;                  // XCD (id%8) pinned to one batch
  const int u   = ((id >> 3) << 1) | (id & 1);    // 0..127 within batch
  const int hg  = u & 3, y = u >> 2;              // 4 head-groups x 32 y-pairs
  const int hh  = hg*4 + w;                       // head
  const int qbs0 = y, qbs1 = 63 - y;
  const int ntA = (y >> 1) + 1, ntT = 33;
  const short* Kb = kvn  + (size_t)b*SEQ*DLKV;    // [t][c]
  const short* Vb = kvnT + (size_t)b*DLKV*SEQ;    // [c][t]
  char* Pw = (char*)Pl[w];

  const short ONE = 0x3F80;
  bf8 ones;
  #pragma unroll
  for (int j2=0;j2<8;j2++) ones[j2] = ONE;
  f4 z = {0.f,0.f,0.f,0.f};

  // ---- segment state (q-block A = light first) ----
  int qw = qbs0*32;
  size_t rowbase = (size_t)b*SEQ + qw;
  bf8 qf[2][4];                                   // Q as B-frag: col=q=l15, k=c
  f4 acc[2][8], sums[2]; float mr[2];
  #pragma unroll
  for (int mi=0;mi<2;mi++) {
    #pragma unroll
    for (int kk=0;kk<4;kk++)
      qf[mi][kk] = *(const bf8*)(qkv + (rowbase + mi*16 + l15)*NKV + hh*128 + kk*32 + p*8);
    sums[mi] = z;
    #pragma unroll
    for (int cf=0;cf<8;cf++) acc[mi][cf] = z;
    mr[mi] = -3.0e38f;
  }

  // prologue: stage tile 0 into buf 0 (1024 16B chunks, 4 per thread)
  #pragma unroll
  for (int r=0;r<4;r++) {
    int ci = r*256 + tid, row = ci >> 4, c16 = ci & 15;
    gld16(Ks[0] + ci*16, (const char*)Kb + row*256 + ((c16 ^ (row & 7))*16));
  }
  int cur = 0, t = 0;
  for (int j = 0; j < ntT; ++j) {
    const int tn = (j+1 >= ntT) ? t : ((j+1 == ntA) ? 0 : t+1);
    {
      const char* src = (const char*)(Kb + (size_t)tn*64*DLKV);
      #pragma unroll
      for (int r=0;r<4;r++) {
        int ci = r*256 + tid, row = ci >> 4, c16 = ci & 15;
        gld16(Ks[cur^1] + ci*16, src + row*256 + ((c16 ^ (row & 7))*16));
      }
    }
    asm volatile("s_waitcnt vmcnt(4)" ::: "memory");  // current tile's 4 stage-loads done
    __syncthreads();
    const int t0 = t*64;
    const char* kb = Ks[cur];
    // ---- swapped QK^T: sc[mi][tf] = K·Q^T -> row=t (p,r), col=q (l15); exp2-domain ----
    f4 sc[2][4];
    #pragma unroll
    for (int mi=0;mi<2;mi++)
      #pragma unroll
      for (int tf=0;tf<4;tf++) sc[mi][tf] = z;
    #pragma unroll
    for (int kk=0;kk<4;kk++) {
      bf8 bk[4];
      #pragma unroll
      for (int tf=0;tf<4;tf++) { int tt = tf*16 + l15;
        bk[tf] = *(const bf8*)(kb + tt*256 + ((kk*64 + p*16) ^ ((tt&7)<<4))); }
      #pragma unroll
      for (int mi=0;mi<2;mi++)
        #pragma unroll
        for (int tf=0;tf<4;tf++) sc[mi][tf] = MFMA16(bk[tf], qf[mi][kk], sc[mi][tf]);
    }
    if (t0 + 63 > qw) {   // diagonal: causal mask (t in regs, q = l15)
      #pragma unroll
      for (int mi=0;mi<2;mi++) {
        int qg = qw + mi*16 + l15;
        #pragma unroll
        for (int tf=0;tf<4;tf++)
          #pragma unroll
          for (int r=0;r<4;r++) {
            int tg = t0 + tf*16 + 4*p + r;
            if (tg > qg) sc[mi][tf][r] = -3.0e38f;
          }
      }
    }
    // ---- online softmax: in-lane max tree + 2 shfl; defer-max rescale (THR=8) ----
    float pmax[2];
    #pragma unroll
    for (int mi=0;mi<2;mi++) {
      float v = -3.0e38f;
      #pragma unroll
      for (int tf=0;tf<4;tf++)
        #pragma unroll
        for (int r=0;r<4;r++) v = fmaxf(v, sc[mi][tf][r]);
      v = fmaxf(v, __shfl_xor(v, 16));
      v = fmaxf(v, __shfl_xor(v, 32));
      pmax[mi] = v;
    }
    bool need = (pmax[0] > mr[0] + 8.0f) || (pmax[1] > mr[1] + 8.0f);
    if (__any(need)) {
      #pragma unroll
      for (int mi=0;mi<2;mi++) {
        float m2 = fmaxf(mr[mi], pmax[mi]);
        float al = exp2f(mr[mi] - m2);         // indexed by q = l15
        mr[mi] = m2;
        #pragma unroll
        for (int r=0;r<4;r++) {                // broadcast col->(p,r): src lane l15 = 4p+r
          float alq = __shfl(al, (l & 48) + (p << 2) + r);
          sums[mi][r] *= alq;
          #pragma unroll
          for (int cf=0;cf<8;cf++) acc[mi][cf][r] *= alq;
        }
      }
    }
    // ---- P = exp2(sc - m): cvt_pk pairs (t-adjacent in regs) -> ds_write_b64 ----
    #pragma unroll
    for (int mi=0;mi<2;mi++) {
      #pragma unroll
      for (int tf=0;tf<4;tf++) {
        unsigned d0 = cvtpk(exp2f(sc[mi][tf][0] - mr[mi]), exp2f(sc[mi][tf][1] - mr[mi]));
        unsigned d1 = cvtpk(exp2f(sc[mi][tf][2] - mr[mi]), exp2f(sc[mi][tf][3] - mr[mi]));
        u2 dd; dd.x = d0; dd.y = d1;
        *(u2*)(Pw + (mi*16 + l15)*144 + tf*32 + p*8) = dd;   // [q][t], t = tf*16+4p..+3
      }
    }
    // ---- PV: acc += P·V, sums += P·1 ; V inline per-kk batch (L2-resident) ----
    #pragma unroll
    for (int kk=0;kk<2;kk++) {
      bf8 pa[2];
      #pragma unroll
      for (int mi=0;mi<2;mi++)
        pa[mi] = *(const bf8*)(Pw + (mi*16 + l15)*144 + kk*64 + p*16);
      #pragma unroll
      for (int mi=0;mi<2;mi++) sums[mi] = MFMA16(pa[mi], ones, sums[mi]);
      #pragma unroll
      for (int cf=0;cf<8;cf++) {
        bf8 bv = *(const bf8*)(Vb + (size_t)(cf*16 + l15)*SEQ + t0 + kk*32 + p*8);
        #pragma unroll
        for (int mi=0;mi<2;mi++) acc[mi][cf] = MFMA16(pa[mi], bv, acc[mi][cf]);
      }
    }
    __syncthreads();   // protect Ks[cur] from next iteration's staging
    cur ^= 1;
    // ---- segment boundary: write out, reinit for q-block B ----
    if (j+1 == ntA || j+1 == ntT) {
      #pragma unroll
      for (int mi=0;mi<2;mi++) {
        float inv[4];
        #pragma unroll
        for (int r=0;r<4;r++) inv[r] = 1.0f / sums[mi][r];
        #pragma unroll
        for (int cf=0;cf<8;cf++)
          #pragma unroll
          for (int r=0;r<4;r++) {
            size_t m = rowbase + mi*16 + 4*p + r;
            vlat[m*NKV + hh*128 + cf*16 + l15] = f2b(acc[mi][cf][r] * inv[r]);
          }
      }
      if (j+1 == ntA) {
        qw = qbs1*32; rowbase = (size_t)b*SEQ + qw;
        #pragma unroll
        for (int mi=0;mi<2;mi++) {
          #pragma unroll
          for (int kk=0;kk<4;kk++)
            qf[mi][kk] = *(const bf8*)(qkv + (rowbase + mi*16 + l15)*NKV + hh*128 + kk*32 + p*8);
          sums[mi] = z;
          #pragma unroll
          for (int cf=0;cf<8;cf++) acc[mi][cf] = z;
          mr[mi] = -3.0e38f;
        }
      }
    }
    t = tn;
  }
}

extern "C" void kernel_launch(void* const* d_in, const int* in_sizes, int n_in,
                              void* d_out, int out_size, void* d_ws, size_t ws_size,
                              hipStream_t stream) {
  const float* h     = (const float*)d_in[0];
  const float* wqaw  = (const float*)d_in[2];
  const float* wqa_b = (const float*)d_in[3];
  const float* qnw   = (const float*)d_in[4];
  const float* wqbw  = (const float*)d_in[5];
  const float* wqbb  = (const float*)d_in[6];
  const float* wkvaw = (const float*)d_in[7];
  const float* wkva_b= (const float*)d_in[8];
  const float* kvnw  = (const float*)d_in[9];
  const float* wkvb  = (const float*)d_in[10];
  const float* wow   = (const float*)d_in[11];
  const float* wob   = (const float*)d_in[12];

  char* ws = (char*)d_ws;
  size_t off = 0;
  auto alloc = [&](size_t bytes) { char* p = ws + off; off += (bytes + 255) & ~(size_t)255; return p; };
  short* hb     = (short*)alloc((size_t)MR*DM*2);
  short* wqab16 = (short*)alloc((size_t)DLQ*DM*2);
  short* wkvab16= (short*)alloc((size_t)DLKV*DM*2);
  short* qlat   = (short*)alloc((size_t)MR*DLQ*2);
  short* kvnb   = (short*)alloc((size_t)MR*DLKV*2);
  short* kvnT   = (short*)alloc((size_t)MR*DLKV*2);
  short* Wc     = (short*)alloc((size_t)NKV*DLQ*2);
  float* bc     = (float*)alloc((size_t)NKV*4);
  short* qkv    = (short*)alloc((size_t)MR*NKV*2);
  short* vlat   = (short*)alloc((size_t)MR*NKV*2);
  short* W2     = (short*)alloc((size_t)DM*NKV*2);

  k_conv<<<2048, 256, 0, stream>>>(h, wqaw, wkvaw, hb, wqab16, wkvab16);
  k_wcomb<<<NKV, 256, 0, stream>>>(wqbw, wqbb, wkvb, Wc, bc);
  k_w2<<<(DM*NKV)/256, 256, 0, stream>>>(wow, wkvb, W2);
  k_proj_rms<DLQ,  false><<<MR/32, 256, 0, stream>>>(hb, wqab16,  wqa_b,  qnw,  qlat, nullptr);
  k_proj_rms<DLKV, true ><<<MR/32, 256, 0, stream>>>(hb, wkvab16, wkva_b, kvnw, kvnb, kvnT);
  k_gemm<true ><<<dim3(NKV/128, MR/128), 256, 0, stream>>>(qlat, Wc, bc, qkv, NKV, DLQ);
  k_flash<<<512, 256, 0, stream>>>(qkv, kvnb, kvnT, vlat);
  k_gemm<false><<<dim3(DM/128, MR/128), 256, 0, stream>>>(vlat, W2, wob, d_out, DM, NKV);
}